// Round 13
// baseline (25075.285 us; speedup 1.0000x reference)
//
#include <hip/hip_runtime.h>
#include <math.h>
#include <stdint.h>

#define T_SEQ 4096

__device__ __forceinline__ float sigm(float x) { return 1.0f / (1.0f + expf(-x)); }

// ---------------------------------------------------------------------------
// fp32 NT GEMM with bias: layer-0 preactivations for both branches.
// Output layout: G[t][b][br][16] — both branches' 16 gate preacts for
// recurrence-block b at step t form ONE 128-byte line (exactly one HBM
// line per block-tick in the recurrence).
// ---------------------------------------------------------------------------
__global__ void __launch_bounds__(256) gemm_nt_bias(
    const float* __restrict__ A0, const float* __restrict__ A1,
    const float* __restrict__ B,
    const float* __restrict__ bias1, const float* __restrict__ bias2,
    float* __restrict__ C)
{
    const int t  = threadIdx.x;
    const int tx = t & 15, ty = t >> 4;
    const int n0 = blockIdx.x * 128, m0 = blockIdx.y * 128;
    const float* Ab = (m0 < 4096) ? A0 : A1;
    const int ml0 = (m0 < 4096) ? m0 : (m0 - 4096);

    __shared__ float As[16 * 140];
    __shared__ float Bs[16 * 140];

    const int lr = t >> 1;
    const int lh = t & 1;
    const int pw = lr + ((lr >> 5) << 2);
    const int pa = ty * 8 + ((ty >> 2) << 2);
    const int pb = tx * 8 + ((tx >> 2) << 2);

    float acc[8][8];
#pragma unroll
    for (int i = 0; i < 8; ++i)
#pragma unroll
        for (int j = 0; j < 8; ++j) acc[i][j] = 0.f;

    for (int k0 = 0; k0 < 1024; k0 += 16) {
        const float* ap = Ab + (size_t)(ml0 + lr) * 1024 + k0 + lh * 8;
        float4 av0 = *(const float4*)ap;
        float4 av1 = *(const float4*)(ap + 4);
        const float* bp = B + (size_t)(n0 + lr) * 1024 + k0 + lh * 8;
        float4 bv0 = *(const float4*)bp;
        float4 bv1 = *(const float4*)(bp + 4);

        __syncthreads();
        const int kb = lh * 8;
        As[(kb + 0) * 140 + pw] = av0.x;  As[(kb + 1) * 140 + pw] = av0.y;
        As[(kb + 2) * 140 + pw] = av0.z;  As[(kb + 3) * 140 + pw] = av0.w;
        As[(kb + 4) * 140 + pw] = av1.x;  As[(kb + 5) * 140 + pw] = av1.y;
        As[(kb + 6) * 140 + pw] = av1.z;  As[(kb + 7) * 140 + pw] = av1.w;
        Bs[(kb + 0) * 140 + pw] = bv0.x;  Bs[(kb + 1) * 140 + pw] = bv0.y;
        Bs[(kb + 2) * 140 + pw] = bv0.z;  Bs[(kb + 3) * 140 + pw] = bv0.w;
        Bs[(kb + 4) * 140 + pw] = bv1.x;  Bs[(kb + 5) * 140 + pw] = bv1.y;
        Bs[(kb + 6) * 140 + pw] = bv1.z;  Bs[(kb + 7) * 140 + pw] = bv1.w;
        __syncthreads();

#pragma unroll
        for (int kk = 0; kk < 16; ++kk) {
            float4 a0 = *(const float4*)&As[kk * 140 + pa];
            float4 a1 = *(const float4*)&As[kk * 140 + pa + 4];
            float4 b0 = *(const float4*)&Bs[kk * 140 + pb];
            float4 b1 = *(const float4*)&Bs[kk * 140 + pb + 4];
            float a[8]  = {a0.x, a0.y, a0.z, a0.w, a1.x, a1.y, a1.z, a1.w};
            float bb[8] = {b0.x, b0.y, b0.z, b0.w, b1.x, b1.y, b1.z, b1.w};
#pragma unroll
            for (int i = 0; i < 8; ++i)
#pragma unroll
                for (int j = 0; j < 8; ++j)
                    acc[i][j] = fmaf(a[i], bb[j], acc[i][j]);
        }
    }

    const int gcol  = n0 >> 10;              // gate for this whole block-column
    const int qbase = (n0 & 1023) + tx * 8;  // 4b+u base
    const int j0 = n0 + tx * 8;
    float bsv[8];
#pragma unroll
    for (int j = 0; j < 8; ++j) bsv[j] = bias1[j0 + j] + bias2[j0 + j];
#pragma unroll
    for (int i = 0; i < 8; ++i) {
        const int mg = m0 + ty * 8 + i;            // 0..8191 (branch-major)
        const int br = mg >> 12;                   // 0 / 1
        const size_t mrow = (size_t)(mg & 4095) * 8192;
#pragma unroll
        for (int jj = 0; jj < 8; ++jj) {
            const int q = qbase + jj;              // 4b+u
            C[mrow + ((size_t)(q >> 2) << 5) + (br << 4) + (gcol << 2) + (q & 3)]
                = acc[i][jj] + bsv[jj];
        }
    }
}

// ---------------------------------------------------------------------------
// Fused layer-pipelined LSTM recurrence.
// 256 blocks x 512 threads, plain launch; 147 KB LDS forces 1 block/CU on
// 256 CUs => all blocks co-resident, spin-waits make progress.
// Tick tau: layer0 step tau, layer1 step tau-1.
//
// R13 = R9's PROVEN kernel (tag-store sync, wave0-only u64 polling — ran
// at 23.2 ms) with exactly ONE change: w1h/w1i move to LDS in a [m][t]
// float4 layout. Rationale: R9 showed VGPR=92 < its 96 pinned weight
// scalars — the allocator spilled pinned weights to scratch (WRITE_SIZE
// stuck at 160 MB, ~90 MB above h-store volume, per-tick scratch reloads
// hiding in L2). With only w0 in registers (32 scalars + ~40 working ~=
// 75 VGPR) the spill is structurally impossible. The [m][t] layout makes
// each lane read consecutive 16 B (w[m*512+t]) — canonical conflict-free
// LDS access, NOT R8's row-major layout that caused 545M bank conflicts.
// (R10-R12's fetch_add-counter syncs all died in-container; sync stays
// on the proven store-tag design.)
//
// TRANSPORT (R9-proven): producers store 16 h floats (relaxed agent
// atomics), drain vmcnt(0), one lane publishes tag[tau&1][b]=tau+2.
// Consumers: WAVE 0 ONLY polls — lane l covers tags 4l..4l+3 via two
// atomic u64 loads with s_sleep(2) backoff; __syncthreads() orders the
// observation before all staging loads. Ring-of-2 safety: a buffer is
// only overwritten two ticks after every block proved (via its tag) it
// finished reading it; tags monotonic per run, memset re-zeroed per
// replay, so no ABA.
// ---------------------------------------------------------------------------
__global__ void
__attribute__((amdgpu_flat_work_group_size(512, 512), amdgpu_waves_per_eu(2, 2)))
lstm_fused(
    const float* __restrict__ W_hh,  // [2][4096][1024]
    const float* __restrict__ W_ih,  // [2][4096][1024]
    const float* __restrict__ b_ih,  // [2][4096]
    const float* __restrict__ b_hh,  // [2][4096]
    const float* __restrict__ G,     // [T][256][2][16] permuted layer-0 preacts
    const float* __restrict__ h1_0, const float* __restrict__ c1_0,
    const float* __restrict__ h2_0, const float* __restrict__ c2_0,
    float* hbf,                      // [2 buf][2 layer][2 br][1024] h ring
                                     //   (low 8KB doubles as o_out)
    uint32_t* tag)                   // [2 buf][256 producers]
{
    const int b = blockIdx.x, t = threadIdx.x;
    const int row = t & 15;          // gate-unit row (16 per block)
    const int slice = t >> 4;        // 0..31, each covers 32 h-elements
    const int gate = row >> 2, uoff = row & 3;
    const int j_glob = gate * 1024 + b * 4 + uoff;

    __shared__ float hs[4096];         // [4 vec][1024]
    __shared__ float red[8][4][16];    // [wave][acc][row]
    __shared__ float bl1s[16];         // layer-1 bias for owned rows
    __shared__ float4 w1hL[8 * 512];   // layer-1 W_hh, [m][t] (conflict-free)
    __shared__ float4 w1iL[8 * 512];   // layer-1 W_ih, [m][t]

    // ---- layer-0 weights -> registers; layer-1 weights -> LDS [m][t] ----
    float4 w0[8];
    {
        const float* r0 = W_hh + (size_t)j_glob * 1024 + slice * 32;
        const float* r1 = W_hh + 4194304ull + (size_t)j_glob * 1024 + slice * 32;
        const float* r2 = W_ih + 4194304ull + (size_t)j_glob * 1024 + slice * 32;
#pragma unroll
        for (int m = 0; m < 8; ++m) {
            const int o = ((m + slice + 2 * row) & 7) << 2;
            w0[m]             = *(const float4*)(r0 + o);
            w1hL[m * 512 + t] = *(const float4*)(r1 + o);
            w1iL[m * 512 + t] = *(const float4*)(r2 + o);
        }
    }
    // Anti-sinking insurance for the 32 register-resident scalars.
#pragma unroll
    for (int m = 0; m < 8; ++m)
        asm volatile(""
            : "+v"(w0[m].x), "+v"(w0[m].y), "+v"(w0[m].z), "+v"(w0[m].w));

    float creg = 0.f;
    if (t < 16) {
        const int layer = t >> 3, br = (t >> 2) & 1, u = t & 3;
        const float* cc = br ? c2_0 : c1_0;
        const float* hh = br ? h2_0 : h1_0;
        creg = cc[layer * 1024 + b * 4 + u];
        const float hinit = hh[layer * 1024 + b * 4 + u];
        // init h -> buffer1 (consumed at tick 0)
        __hip_atomic_store(hbf + 4096 + layer * 2048 + br * 1024 + b * 4 + u,
                           hinit, __ATOMIC_RELAXED, __HIP_MEMORY_SCOPE_AGENT);
        // layer-1 init also -> buffer0 (consumed at tick 1; layer-1 is
        // inactive at tick 0 so nothing else writes these slots; covered
        // by tag[0][b]=2 published at end of tick 0, after these stores).
        if (layer == 1)
            __hip_atomic_store(hbf + 2048 + br * 1024 + b * 4 + u,
                               hinit, __ATOMIC_RELAXED, __HIP_MEMORY_SCOPE_AGENT);
    }
    if (t >= 32 && t < 48) {
        const int rr = t & 15;
        const int jj = 4096 + (rr >> 2) * 1024 + b * 4 + (rr & 3);
        bl1s[rr] = b_ih[jj] + b_hh[jj];
    }
    if (t < 64) {
        asm volatile("s_waitcnt vmcnt(0)" ::: "memory");  // init h at LLC
        if (t == 0)
            __hip_atomic_store(tag + 256 + b, 1u,
                               __ATOMIC_RELAXED, __HIP_MEMORY_SCOPE_AGENT);
    }
    __syncthreads();   // also covers the weight LDS staging

    for (int tick = 0; tick <= T_SEQ; ++tick) {
        // ---- layer-0 G prefetch first (one 128 B line per block-tick) ----
        float gpre = 0.f;
        if (t < 32) {
            const int br = t >> 4, rr = t & 15;
            const int st = (tick < T_SEQ) ? tick : (T_SEQ - 1);
            gpre = G[(size_t)st * 8192 + b * 32 + (br << 4) + rr];
        }

        // ---- tag wait: WAVE 0 ONLY; lane l covers tags 4l..4l+3 ----
        if (t < 64) {
            const uint64_t* tg =
                (const uint64_t*)(tag + ((tick + 1) & 1) * 256) + (t << 1);
            const uint32_t want = (uint32_t)tick + 1u;
            for (;;) {
                uint64_t v0 = __hip_atomic_load(tg, __ATOMIC_RELAXED,
                                                __HIP_MEMORY_SCOPE_AGENT);
                uint64_t v1 = __hip_atomic_load(tg + 1, __ATOMIC_RELAXED,
                                                __HIP_MEMORY_SCOPE_AGENT);
                if ((uint32_t)v0 >= want && (uint32_t)(v0 >> 32) >= want &&
                    (uint32_t)v1 >= want && (uint32_t)(v1 >> 32) >= want)
                    break;
                __builtin_amdgcn_s_sleep(2);
            }
        }
        __syncthreads();   // wave 0 saw all 256 tags -> all h data at LLC

        // ---- stage h_prev: guaranteed-ready batched atomic loads ----
        {
            const float* src = hbf + ((tick + 1) & 1) * 4096;
            float v[8];
#pragma unroll
            for (int r = 0; r < 8; ++r)
                v[r] = __hip_atomic_load(src + t + r * 512, __ATOMIC_RELAXED,
                                         __HIP_MEMORY_SCOPE_AGENT);
#pragma unroll
            for (int r = 0; r < 8; ++r)
                hs[t + r * 512] = v[r];
        }
        __syncthreads();

        // ---- 3 matvecs over owned rows (8 rotated float4 chunks each) ----
        float a00 = 0.f, a01 = 0.f, a10 = 0.f, a11 = 0.f;
        const float4* H00 = (const float4*)hs;
        const float4* H01 = (const float4*)(hs + 1024);
        const float4* H10 = (const float4*)(hs + 2048);
        const float4* H11 = (const float4*)(hs + 3072);
#pragma unroll
        for (int m = 0; m < 8; ++m) {
            const int ci = (slice << 3) + ((m + slice + 2 * row) & 7);
            const float4 x0 = H00[ci], x1 = H01[ci];
            const float4 y0 = H10[ci], y1 = H11[ci];
            const float4 wh = w1hL[m * 512 + t];
            const float4 wi = w1iL[m * 512 + t];
            a00 = fmaf(w0[m].x, x0.x, a00); a00 = fmaf(w0[m].y, x0.y, a00);
            a00 = fmaf(w0[m].z, x0.z, a00); a00 = fmaf(w0[m].w, x0.w, a00);
            a01 = fmaf(w0[m].x, x1.x, a01); a01 = fmaf(w0[m].y, x1.y, a01);
            a01 = fmaf(w0[m].z, x1.z, a01); a01 = fmaf(w0[m].w, x1.w, a01);
            a10 = fmaf(wi.x, x0.x, a10); a10 = fmaf(wi.y, x0.y, a10);
            a10 = fmaf(wi.z, x0.z, a10); a10 = fmaf(wi.w, x0.w, a10);
            a10 = fmaf(wh.x, y0.x, a10); a10 = fmaf(wh.y, y0.y, a10);
            a10 = fmaf(wh.z, y0.z, a10); a10 = fmaf(wh.w, y0.w, a10);
            a11 = fmaf(wi.x, x1.x, a11); a11 = fmaf(wi.y, x1.y, a11);
            a11 = fmaf(wi.z, x1.z, a11); a11 = fmaf(wi.w, x1.w, a11);
            a11 = fmaf(wh.x, y1.x, a11); a11 = fmaf(wh.y, y1.y, a11);
            a11 = fmaf(wh.z, y1.z, a11); a11 = fmaf(wh.w, y1.w, a11);
        }
        // sum the 4 slices within each wave
        a00 += __shfl_xor(a00, 16); a00 += __shfl_xor(a00, 32);
        a01 += __shfl_xor(a01, 16); a01 += __shfl_xor(a01, 32);
        a10 += __shfl_xor(a10, 16); a10 += __shfl_xor(a10, 32);
        a11 += __shfl_xor(a11, 16); a11 += __shfl_xor(a11, 32);
        const int wv = t >> 6, lane = t & 63;
        if (lane < 16) {
            red[wv][0][lane] = a00; red[wv][1][lane] = a01;
            red[wv][2][lane] = a10; red[wv][3][lane] = a11;
        }
        __syncthreads();

        // ---- tail: wave 0 only (red[] reuse is safe: other waves' next
        //      red-write sits behind the next post-staging __syncthreads,
        //      which waits for wave 0 to finish this tail) ----
        if (t < 64) {
            const int lb = t >> 4, rr = t & 15;
            float s = red[0][lb][rr] + red[1][lb][rr] + red[2][lb][rr] + red[3][lb][rr]
                    + red[4][lb][rr] + red[5][lb][rr] + red[6][lb][rr] + red[7][lb][rr];
            s += (lb < 2) ? gpre : bl1s[rr];
            // lane lb*16+rr holds gate (rr>>2) of unit (rr&3), layer=lb>>1, br=lb&1
            const int src0 = ((t >> 2) << 4) + (t & 3);   // meaningful for t<16
            const float gi = __shfl(s, src0);
            const float gf = __shfl(s, src0 + 4);
            const float gg = __shfl(s, src0 + 8);
            const float go = __shfl(s, src0 + 12);
            if (t < 16) {
                const int layer = t >> 3, br = (t >> 2) & 1, u = t & 3;
                const bool active = (layer == 0) ? (tick < T_SEQ) : (tick >= 1);
                if (active) {
                    const float c = sigm(gf) * creg + sigm(gi) * tanhf(gg);
                    const float h = sigm(go) * tanhf(c);
                    creg = c;
                    if (layer == 1 && tick == T_SEQ) {
                        // final output -> dead low 8KB of the ring (buffer0
                        // layer-0 slots; our tick-T_SEQ staging saw all tags
                        // == T_SEQ+1, so every block finished its buffer0
                        // reads; nothing stages buffer0 after this).
                        __hip_atomic_store(hbf + br * 1024 + b * 4 + u, h,
                                           __ATOMIC_RELAXED, __HIP_MEMORY_SCOPE_AGENT);
                    } else {
                        __hip_atomic_store(
                            hbf + (tick & 1) * 4096 + layer * 2048 + br * 1024 + b * 4 + u,
                            h, __ATOMIC_RELAXED, __HIP_MEMORY_SCOPE_AGENT);
                    }
                }
            }
            if (tick < T_SEQ) {
                asm volatile("s_waitcnt vmcnt(0)" ::: "memory");  // h at LLC
                if (t == 0)
                    __hip_atomic_store(tag + (tick & 1) * 256 + b,
                                       (uint32_t)(tick + 2),
                                       __ATOMIC_RELAXED, __HIP_MEMORY_SCOPE_AGENT);
            }
        }
        // no end-of-loop barrier needed: this tick's hs reads completed
        // before the red-barrier above; next staging may overwrite hs freely.
    }
}

// ---------------------------------------------------------------------------
// out = 5*exp(-sum |o1 - o2|)
// ---------------------------------------------------------------------------
__global__ void __launch_bounds__(256) dist_kernel(const float* __restrict__ o,
                                                   float* __restrict__ out)
{
    int t = threadIdx.x;
    float s = 0.f;
    for (int i = t; i < 1024; i += 256) s += fabsf(o[i] - o[i + 1024]);
#pragma unroll
    for (int off = 1; off < 64; off <<= 1) s += __shfl_xor(s, off);
    __shared__ float r[4];
    if ((t & 63) == 0) r[t >> 6] = s;
    __syncthreads();
    if (t == 0) out[0] = 5.0f * expf(-(r[0] + r[1] + r[2] + r[3]));
}

// ---------------------------------------------------------------------------
extern "C" void kernel_launch(void* const* d_in, const int* in_sizes, int n_in,
                              void* d_out, int out_size, void* d_ws, size_t ws_size,
                              hipStream_t stream) {
    const float* s1   = (const float*)d_in[0];
    const float* s2   = (const float*)d_in[1];
    const float* h1_0 = (const float*)d_in[2];
    const float* c1_0 = (const float*)d_in[3];
    const float* h2_0 = (const float*)d_in[4];
    const float* c2_0 = (const float*)d_in[5];
    const float* W_ih = (const float*)d_in[6];
    const float* W_hh = (const float*)d_in[7];
    const float* b_ih = (const float*)d_in[8];
    const float* b_hh = (const float*)d_in[9];

    uint8_t* w8 = (uint8_t*)d_ws;
    float* hbf     = (float*)w8;                 // 32 KB: [2][4096] h ring
                                                 //   (low 8 KB reused as o_out)
    uint32_t* tag  = (uint32_t*)(w8 + 32768);    // 2 KB: [2][256] producer tags
    float* G       = (float*)(w8 + 65536);       // 128 MB: [T][256][2][16]

    hipMemsetAsync(d_ws, 0, 65536, stream);      // zero ring + tags

    // Phase 1: layer-0 input GEMM for both branches (line-merged output)
    dim3 ggrid(32, 64);
    gemm_nt_bias<<<ggrid, 256, 0, stream>>>(s1, s2, W_ih, b_ih, b_hh, G);

    // Phase 2: fused recurrence — plain launch; co-residency guaranteed by
    // 1 block/CU (256 blocks of 512 threads, 147 KB LDS, on 256 CUs).
    lstm_fused<<<dim3(256), dim3(512), 0, stream>>>(
        W_hh, W_ih, b_ih, b_hh, G, h1_0, c1_0, h2_0, c2_0, hbf, tag);

    // Phase 3: scalar output
    dist_kernel<<<1, 256, 0, stream>>>((const float*)d_ws, (float*)d_out);
}

// Round 14
// 16015.668 us; speedup vs baseline: 1.5657x; 1.5657x over previous
//
#include <hip/hip_runtime.h>
#include <math.h>
#include <stdint.h>

#define T_SEQ 4096

__device__ __forceinline__ float sigm(float x) { return 1.0f / (1.0f + expf(-x)); }

// ---------------------------------------------------------------------------
// Fence-free grid barrier, called by WAVE 0 ONLY (t < 64). Verbatim from the
// 16.7 ms baseline (proven: 3.7 us/tick). All cross-block data travels via
// relaxed agent-scope atomics (LLC-coherent on gfx950).
// bar[g*32]       : arrival counter, group g (16 blocks/group), monotonic
// bar[512 + g*32] : release word, group g (stores latest completed ord)
// Block 0 lanes 0..15 poll the 16 counters in parallel, then broadcast.
// Polling load: block0's 16 lanes on 16 arrival lines + 255 single lanes on
// 16 release lines — ~16 requests/line/round, NOT the 256/line/round of the
// R3-R13 tag designs (whose polls queued ahead of the tag stores themselves).
// ---------------------------------------------------------------------------
__device__ __forceinline__ void wave0_barrier(uint32_t* bar, uint32_t ord, int t) {
    if (t == 0)
        __hip_atomic_fetch_add(bar + ((blockIdx.x >> 4) << 5), 1u,
                               __ATOMIC_RELAXED, __HIP_MEMORY_SCOPE_AGENT);
    if (blockIdx.x == 0) {
        if (t < 16) {
            uint32_t* cnt = bar + (t << 5);
            while (__hip_atomic_load(cnt, __ATOMIC_RELAXED, __HIP_MEMORY_SCOPE_AGENT) < (ord << 4))
                __builtin_amdgcn_s_sleep(1);
            // reconvergence: all 16 lanes' loops done -> all 256 blocks arrived
            __hip_atomic_store(bar + 512 + (t << 5), ord,
                               __ATOMIC_RELAXED, __HIP_MEMORY_SCOPE_AGENT);
        }
    } else if (t == 0) {
        uint32_t* rel = bar + 512 + ((blockIdx.x >> 4) << 5);
        while (__hip_atomic_load(rel, __ATOMIC_RELAXED, __HIP_MEMORY_SCOPE_AGENT) < ord)
            __builtin_amdgcn_s_sleep(1);
    }
}

// ---------------------------------------------------------------------------
// fp32 NT GEMM with bias: layer-0 preactivations for both branches.
// Output layout: G[t][b][br][16] — both branches' 16 gate preacts for
// recurrence-block b at step t form ONE 128-byte line.
// ---------------------------------------------------------------------------
__global__ void __launch_bounds__(256) gemm_nt_bias(
    const float* __restrict__ A0, const float* __restrict__ A1,
    const float* __restrict__ B,
    const float* __restrict__ bias1, const float* __restrict__ bias2,
    float* __restrict__ C)
{
    const int t  = threadIdx.x;
    const int tx = t & 15, ty = t >> 4;
    const int n0 = blockIdx.x * 128, m0 = blockIdx.y * 128;
    const float* Ab = (m0 < 4096) ? A0 : A1;
    const int ml0 = (m0 < 4096) ? m0 : (m0 - 4096);

    __shared__ float As[16 * 140];
    __shared__ float Bs[16 * 140];

    const int lr = t >> 1;
    const int lh = t & 1;
    const int pw = lr + ((lr >> 5) << 2);
    const int pa = ty * 8 + ((ty >> 2) << 2);
    const int pb = tx * 8 + ((tx >> 2) << 2);

    float acc[8][8];
#pragma unroll
    for (int i = 0; i < 8; ++i)
#pragma unroll
        for (int j = 0; j < 8; ++j) acc[i][j] = 0.f;

    for (int k0 = 0; k0 < 1024; k0 += 16) {
        const float* ap = Ab + (size_t)(ml0 + lr) * 1024 + k0 + lh * 8;
        float4 av0 = *(const float4*)ap;
        float4 av1 = *(const float4*)(ap + 4);
        const float* bp = B + (size_t)(n0 + lr) * 1024 + k0 + lh * 8;
        float4 bv0 = *(const float4*)bp;
        float4 bv1 = *(const float4*)(bp + 4);

        __syncthreads();
        const int kb = lh * 8;
        As[(kb + 0) * 140 + pw] = av0.x;  As[(kb + 1) * 140 + pw] = av0.y;
        As[(kb + 2) * 140 + pw] = av0.z;  As[(kb + 3) * 140 + pw] = av0.w;
        As[(kb + 4) * 140 + pw] = av1.x;  As[(kb + 5) * 140 + pw] = av1.y;
        As[(kb + 6) * 140 + pw] = av1.z;  As[(kb + 7) * 140 + pw] = av1.w;
        Bs[(kb + 0) * 140 + pw] = bv0.x;  Bs[(kb + 1) * 140 + pw] = bv0.y;
        Bs[(kb + 2) * 140 + pw] = bv0.z;  Bs[(kb + 3) * 140 + pw] = bv0.w;
        Bs[(kb + 4) * 140 + pw] = bv1.x;  Bs[(kb + 5) * 140 + pw] = bv1.y;
        Bs[(kb + 6) * 140 + pw] = bv1.z;  Bs[(kb + 7) * 140 + pw] = bv1.w;
        __syncthreads();

#pragma unroll
        for (int kk = 0; kk < 16; ++kk) {
            float4 a0 = *(const float4*)&As[kk * 140 + pa];
            float4 a1 = *(const float4*)&As[kk * 140 + pa + 4];
            float4 b0 = *(const float4*)&Bs[kk * 140 + pb];
            float4 b1 = *(const float4*)&Bs[kk * 140 + pb + 4];
            float a[8]  = {a0.x, a0.y, a0.z, a0.w, a1.x, a1.y, a1.z, a1.w};
            float bb[8] = {b0.x, b0.y, b0.z, b0.w, b1.x, b1.y, b1.z, b1.w};
#pragma unroll
            for (int i = 0; i < 8; ++i)
#pragma unroll
                for (int j = 0; j < 8; ++j)
                    acc[i][j] = fmaf(a[i], bb[j], acc[i][j]);
        }
    }

    const int gcol  = n0 >> 10;              // gate for this whole block-column
    const int qbase = (n0 & 1023) + tx * 8;  // 4b+u base
    const int j0 = n0 + tx * 8;
    float bsv[8];
#pragma unroll
    for (int j = 0; j < 8; ++j) bsv[j] = bias1[j0 + j] + bias2[j0 + j];
#pragma unroll
    for (int i = 0; i < 8; ++i) {
        const int mg = m0 + ty * 8 + i;            // 0..8191 (branch-major)
        const int br = mg >> 12;                   // 0 / 1
        const size_t mrow = (size_t)(mg & 4095) * 8192;
#pragma unroll
        for (int jj = 0; jj < 8; ++jj) {
            const int q = qbase + jj;              // 4b+u
            C[mrow + ((size_t)(q >> 2) << 5) + (br << 4) + (gcol << 2) + (q & 3)]
                = acc[i][jj] + bsv[jj];
        }
    }
}

// ---------------------------------------------------------------------------
// Fused layer-pipelined LSTM recurrence.
// 256 blocks x 512 threads, plain launch; 147 KB LDS forces 1 block/CU on
// 256 CUs => all blocks co-resident. Tick tau: layer0 step tau, layer1
// step tau-1.
//
// R14 = clean A/B vs R13: identical shell (512 threads, LDS [m][t] weights,
// G line-merge), sync swapped from the contended 1-RT tag poll to the
// baseline's PROVEN 2-RT wave0_barrier. R13 killed the weight theory
// (weights in LDS, VGPR=88 -> zero change); the per-tick gap vs the 3.7us
// baseline must be sync contention: 256 blocks' wave0s polling 8 hot tag
// lines (~256 req/line/round) queue AHEAD of the producers' tag stores on
// those same lines, delaying publication by ~2us/tick. The baseline
// barrier's polls are spread (16+16 lines, ~16 req/line/round) and never
// target producer-written lines.
//
// TRANSPORT: producers store 16 h floats (relaxed agent atomics), wave-
// level vmcnt(0) drain, then grid-barrier. After the barrier + block-level
// __syncthreads, all h is at the LLC: staging is guaranteed-ready batched
// atomic loads. Ring-of-2: barrier at end of tick tau proves every block
// finished its tick-tau staging reads, so tick tau+1's producers may
// overwrite that buffer. Ords monotonic; memset re-zeroes per replay.
// ---------------------------------------------------------------------------
__global__ void
__attribute__((amdgpu_flat_work_group_size(512, 512), amdgpu_waves_per_eu(2, 2)))
lstm_fused(
    const float* __restrict__ W_hh,  // [2][4096][1024]
    const float* __restrict__ W_ih,  // [2][4096][1024]
    const float* __restrict__ b_ih,  // [2][4096]
    const float* __restrict__ b_hh,  // [2][4096]
    const float* __restrict__ G,     // [T][256][2][16] permuted layer-0 preacts
    const float* __restrict__ h1_0, const float* __restrict__ c1_0,
    const float* __restrict__ h2_0, const float* __restrict__ c2_0,
    float* hbf,                      // [2 buf][2 layer][2 br][1024] h ring
                                     //   (low 8KB doubles as o_out)
    uint32_t* bar)                   // 8 KB barrier region
{
    const int b = blockIdx.x, t = threadIdx.x;
    const int row = t & 15;          // gate-unit row (16 per block)
    const int slice = t >> 4;        // 0..31, each covers 32 h-elements
    const int gate = row >> 2, uoff = row & 3;
    const int j_glob = gate * 1024 + b * 4 + uoff;

    __shared__ float hs[4096];         // [4 vec][1024]
    __shared__ float red[8][4][16];    // [wave][acc][row]
    __shared__ float bl1s[16];         // layer-1 bias for owned rows
    __shared__ float4 w1hL[8 * 512];   // layer-1 W_hh, [m][t] (conflict-free)
    __shared__ float4 w1iL[8 * 512];   // layer-1 W_ih, [m][t]

    // ---- layer-0 weights -> registers; layer-1 weights -> LDS [m][t] ----
    float4 w0[8];
    {
        const float* r0 = W_hh + (size_t)j_glob * 1024 + slice * 32;
        const float* r1 = W_hh + 4194304ull + (size_t)j_glob * 1024 + slice * 32;
        const float* r2 = W_ih + 4194304ull + (size_t)j_glob * 1024 + slice * 32;
#pragma unroll
        for (int m = 0; m < 8; ++m) {
            const int o = ((m + slice + 2 * row) & 7) << 2;
            w0[m]             = *(const float4*)(r0 + o);
            w1hL[m * 512 + t] = *(const float4*)(r1 + o);
            w1iL[m * 512 + t] = *(const float4*)(r2 + o);
        }
    }
    // Anti-sinking insurance for the 32 register-resident scalars.
#pragma unroll
    for (int m = 0; m < 8; ++m)
        asm volatile(""
            : "+v"(w0[m].x), "+v"(w0[m].y), "+v"(w0[m].z), "+v"(w0[m].w));

    float creg = 0.f;
    if (t < 16) {
        const int layer = t >> 3, br = (t >> 2) & 1, u = t & 3;
        const float* cc = br ? c2_0 : c1_0;
        const float* hh = br ? h2_0 : h1_0;
        creg = cc[layer * 1024 + b * 4 + u];
        const float hinit = hh[layer * 1024 + b * 4 + u];
        // init h -> buffer1 (consumed at tick 0)
        __hip_atomic_store(hbf + 4096 + layer * 2048 + br * 1024 + b * 4 + u,
                           hinit, __ATOMIC_RELAXED, __HIP_MEMORY_SCOPE_AGENT);
        // layer-1 init also -> buffer0 (consumed at tick 1; layer-1 is
        // inactive at tick 0 so nothing else writes these slots; covered
        // by the barrier at end of tick 0, after these stores).
        if (layer == 1)
            __hip_atomic_store(hbf + 2048 + br * 1024 + b * 4 + u,
                               hinit, __ATOMIC_RELAXED, __HIP_MEMORY_SCOPE_AGENT);
    }
    if (t >= 32 && t < 48) {
        const int rr = t & 15;
        const int jj = 4096 + (rr >> 2) * 1024 + b * 4 + (rr & 3);
        bl1s[rr] = b_ih[jj] + b_hh[jj];
    }
    if (t < 64) {
        asm volatile("s_waitcnt vmcnt(0)" ::: "memory");  // init h at LLC
        wave0_barrier(bar, 1u, t);
    }
    __syncthreads();   // also covers the weight LDS staging

    for (int tick = 0; tick <= T_SEQ; ++tick) {
        // ---- layer-0 G prefetch first (one 128 B line per block-tick) ----
        float gpre = 0.f;
        if (t < 32) {
            const int br = t >> 4, rr = t & 15;
            const int st = (tick < T_SEQ) ? tick : (T_SEQ - 1);
            gpre = G[(size_t)st * 8192 + b * 32 + (br << 4) + rr];
        }

        // ---- stage h_prev: guaranteed-ready batched atomic loads
        //      (prev-iter barrier + end-of-loop __syncthreads) ----
        {
            const float* src = hbf + ((tick + 1) & 1) * 4096;
            float v[8];
#pragma unroll
            for (int r = 0; r < 8; ++r)
                v[r] = __hip_atomic_load(src + t + r * 512, __ATOMIC_RELAXED,
                                         __HIP_MEMORY_SCOPE_AGENT);
#pragma unroll
            for (int r = 0; r < 8; ++r)
                hs[t + r * 512] = v[r];
        }
        __syncthreads();

        // ---- 3 matvecs over owned rows (8 rotated float4 chunks each) ----
        float a00 = 0.f, a01 = 0.f, a10 = 0.f, a11 = 0.f;
        const float4* H00 = (const float4*)hs;
        const float4* H01 = (const float4*)(hs + 1024);
        const float4* H10 = (const float4*)(hs + 2048);
        const float4* H11 = (const float4*)(hs + 3072);
#pragma unroll
        for (int m = 0; m < 8; ++m) {
            const int ci = (slice << 3) + ((m + slice + 2 * row) & 7);
            const float4 x0 = H00[ci], x1 = H01[ci];
            const float4 y0 = H10[ci], y1 = H11[ci];
            const float4 wh = w1hL[m * 512 + t];
            const float4 wi = w1iL[m * 512 + t];
            a00 = fmaf(w0[m].x, x0.x, a00); a00 = fmaf(w0[m].y, x0.y, a00);
            a00 = fmaf(w0[m].z, x0.z, a00); a00 = fmaf(w0[m].w, x0.w, a00);
            a01 = fmaf(w0[m].x, x1.x, a01); a01 = fmaf(w0[m].y, x1.y, a01);
            a01 = fmaf(w0[m].z, x1.z, a01); a01 = fmaf(w0[m].w, x1.w, a01);
            a10 = fmaf(wi.x, x0.x, a10); a10 = fmaf(wi.y, x0.y, a10);
            a10 = fmaf(wi.z, x0.z, a10); a10 = fmaf(wi.w, x0.w, a10);
            a10 = fmaf(wh.x, y0.x, a10); a10 = fmaf(wh.y, y0.y, a10);
            a10 = fmaf(wh.z, y0.z, a10); a10 = fmaf(wh.w, y0.w, a10);
            a11 = fmaf(wi.x, x1.x, a11); a11 = fmaf(wi.y, x1.y, a11);
            a11 = fmaf(wi.z, x1.z, a11); a11 = fmaf(wi.w, x1.w, a11);
            a11 = fmaf(wh.x, y1.x, a11); a11 = fmaf(wh.y, y1.y, a11);
            a11 = fmaf(wh.z, y1.z, a11); a11 = fmaf(wh.w, y1.w, a11);
        }
        // sum the 4 slices within each wave
        a00 += __shfl_xor(a00, 16); a00 += __shfl_xor(a00, 32);
        a01 += __shfl_xor(a01, 16); a01 += __shfl_xor(a01, 32);
        a10 += __shfl_xor(a10, 16); a10 += __shfl_xor(a10, 32);
        a11 += __shfl_xor(a11, 16); a11 += __shfl_xor(a11, 32);
        const int wv = t >> 6, lane = t & 63;
        if (lane < 16) {
            red[wv][0][lane] = a00; red[wv][1][lane] = a01;
            red[wv][2][lane] = a10; red[wv][3][lane] = a11;
        }
        __syncthreads();

        // ---- tail: wave 0 only ----
        if (t < 64) {
            const int lb = t >> 4, rr = t & 15;
            float s = red[0][lb][rr] + red[1][lb][rr] + red[2][lb][rr] + red[3][lb][rr]
                    + red[4][lb][rr] + red[5][lb][rr] + red[6][lb][rr] + red[7][lb][rr];
            s += (lb < 2) ? gpre : bl1s[rr];
            // lane lb*16+rr holds gate (rr>>2) of unit (rr&3), layer=lb>>1, br=lb&1
            const int src0 = ((t >> 2) << 4) + (t & 3);   // meaningful for t<16
            const float gi = __shfl(s, src0);
            const float gf = __shfl(s, src0 + 4);
            const float gg = __shfl(s, src0 + 8);
            const float go = __shfl(s, src0 + 12);
            if (t < 16) {
                const int layer = t >> 3, br = (t >> 2) & 1, u = t & 3;
                const bool active = (layer == 0) ? (tick < T_SEQ) : (tick >= 1);
                if (active) {
                    const float c = sigm(gf) * creg + sigm(gi) * tanhf(gg);
                    const float h = sigm(go) * tanhf(c);
                    creg = c;
                    if (layer == 1 && tick == T_SEQ) {
                        // final output -> dead low 8KB of the ring (buffer0
                        // layer-0 slots; the tick-(T_SEQ-1) barrier proved
                        // every block finished its buffer0 reads; nothing
                        // stages buffer0 after this).
                        __hip_atomic_store(hbf + br * 1024 + b * 4 + u, h,
                                           __ATOMIC_RELAXED, __HIP_MEMORY_SCOPE_AGENT);
                    } else {
                        __hip_atomic_store(
                            hbf + (tick & 1) * 4096 + layer * 2048 + br * 1024 + b * 4 + u,
                            h, __ATOMIC_RELAXED, __HIP_MEMORY_SCOPE_AGENT);
                    }
                }
            }
            if (tick < T_SEQ) {
                asm volatile("s_waitcnt vmcnt(0)" ::: "memory");  // h at LLC
                wave0_barrier(bar, (uint32_t)tick + 2u, t);
            }
        }
        __syncthreads();   // wave0's barrier exit gates all waves' next staging
    }
}

// ---------------------------------------------------------------------------
// out = 5*exp(-sum |o1 - o2|)
// ---------------------------------------------------------------------------
__global__ void __launch_bounds__(256) dist_kernel(const float* __restrict__ o,
                                                   float* __restrict__ out)
{
    int t = threadIdx.x;
    float s = 0.f;
    for (int i = t; i < 1024; i += 256) s += fabsf(o[i] - o[i + 1024]);
#pragma unroll
    for (int off = 1; off < 64; off <<= 1) s += __shfl_xor(s, off);
    __shared__ float r[4];
    if ((t & 63) == 0) r[t >> 6] = s;
    __syncthreads();
    if (t == 0) out[0] = 5.0f * expf(-(r[0] + r[1] + r[2] + r[3]));
}

// ---------------------------------------------------------------------------
extern "C" void kernel_launch(void* const* d_in, const int* in_sizes, int n_in,
                              void* d_out, int out_size, void* d_ws, size_t ws_size,
                              hipStream_t stream) {
    const float* s1   = (const float*)d_in[0];
    const float* s2   = (const float*)d_in[1];
    const float* h1_0 = (const float*)d_in[2];
    const float* c1_0 = (const float*)d_in[3];
    const float* h2_0 = (const float*)d_in[4];
    const float* c2_0 = (const float*)d_in[5];
    const float* W_ih = (const float*)d_in[6];
    const float* W_hh = (const float*)d_in[7];
    const float* b_ih = (const float*)d_in[8];
    const float* b_hh = (const float*)d_in[9];

    uint8_t* w8 = (uint8_t*)d_ws;
    float* hbf     = (float*)w8;                 // 32 KB: [2][4096] h ring
                                                 //   (low 8 KB reused as o_out)
    uint32_t* bar  = (uint32_t*)(w8 + 32768);    // 8 KB barrier region
    float* G       = (float*)(w8 + 65536);       // 128 MB: [T][256][2][16]

    hipMemsetAsync(d_ws, 0, 65536, stream);      // zero ring + barrier

    // Phase 1: layer-0 input GEMM for both branches (line-merged output)
    dim3 ggrid(32, 64);
    gemm_nt_bias<<<ggrid, 256, 0, stream>>>(s1, s2, W_ih, b_ih, b_hh, G);

    // Phase 2: fused recurrence — plain launch; co-residency guaranteed by
    // 1 block/CU (256 blocks of 512 threads, 147 KB LDS, on 256 CUs).
    lstm_fused<<<dim3(256), dim3(512), 0, stream>>>(
        W_hh, W_ih, b_ih, b_hh, G, h1_0, c1_0, h2_0, c2_0, hbf, bar);

    // Phase 3: scalar output
    dist_kernel<<<1, 256, 0, stream>>>((const float*)d_ws, (float*)d_out);
}